// Round 1
// baseline (185.955 us; speedup 1.0000x reference)
//
#include <hip/hip_runtime.h>

#define HH 128
#define WW 128
#define CC 96
#define KK 7

// Each block: 256 threads, covers one (b,c) plane half: 64 rows x 128 cols.
// Thread t: col-group cg = t&31 -> out cols [4*cg, 4*cg+4); row-group rg = t>>5
// -> out rows [half*64 + 8*rg, +8). Per thread: 8x4 outputs via a 7x12
// register ring window sliding vertically.

__device__ __forceinline__ void load_row(float* d, const float* __restrict__ xp,
                                         int r, int tc0, bool lok, bool rok) {
  if ((unsigned)r < (unsigned)HH) {
    const float* p = xp + r * WW + tc0 - 4;
    float4 a, b, c;
    if (lok) a = *(const float4*)(p);
    else     a = make_float4(0.f, 0.f, 0.f, 0.f);
    b = *(const float4*)(p + 4);
    if (rok) c = *(const float4*)(p + 8);
    else     c = make_float4(0.f, 0.f, 0.f, 0.f);
    d[0] = a.x; d[1] = a.y; d[2] = a.z; d[3] = a.w;
    d[4] = b.x; d[5] = b.y; d[6] = b.z; d[7] = b.w;
    d[8] = c.x; d[9] = c.y; d[10] = c.z; d[11] = c.w;
  } else {
#pragma unroll
    for (int i = 0; i < 12; ++i) d[i] = 0.f;
  }
}

__global__ __launch_bounds__(256) void morph_kernel(
    const float* __restrict__ x, const float* __restrict__ weight,
    float* __restrict__ out) {
  const int t = threadIdx.x;
  const int cg = t & 31;   // col group 0..31
  const int rg = t >> 5;   // row group 0..7
  const int half = blockIdx.x & 1;
  const int plane = blockIdx.x >> 1;  // b*CC + c
  const int c = plane % CC;

  const float* __restrict__ xp = x + (size_t)plane * (HH * WW);
  float* __restrict__ op = out + (size_t)plane * (HH * WW);
  const float* __restrict__ Wc = weight + c * (KK * KK);

  // Preload 49 channel weights; force into SGPRs (block-uniform).
  float wv[KK * KK];
#pragma unroll
  for (int k = 0; k < KK * KK; ++k)
    wv[k] = __int_as_float(__builtin_amdgcn_readfirstlane(__float_as_int(Wc[k])));

  const int tc0 = cg << 2;              // first out col of this thread
  const int row0 = half * 64 + rg * 8;  // first out row of this thread
  const bool lok = (tc0 >= 4);
  const bool rok = (tc0 <= WW - 8);

  // Ring window: rows row0-3 .. (sliding), 12 cols = [tc0-4, tc0+8)
  float win[7][12];
#pragma unroll
  for (int s = 0; s < 6; ++s)
    load_row(win[s], xp, row0 - 3 + s, tc0, lok, rok);

#pragma unroll
  for (int orow = 0; orow < 8; ++orow) {
    load_row(win[(orow + 6) % 7], xp, row0 + 3 + orow, tc0, lok, rok);

    // ReLU folded in: acc starts at 0 (= max(0, .)).
    float a0 = 0.f, a1 = 0.f, a2 = 0.f, a3 = 0.f;
#pragma unroll
    for (int i = 0; i < 7; ++i) {
      const float* rw = win[(orow + i) % 7];
#pragma unroll
      for (int j = 0; j < 7; ++j) {
        const float wt = wv[i * 7 + j];
        a0 = fmaxf(a0, rw[j + 1] + wt);
        a1 = fmaxf(a1, rw[j + 2] + wt);
        a2 = fmaxf(a2, rw[j + 3] + wt);
        a3 = fmaxf(a3, rw[j + 4] + wt);
      }
    }
    float4 o = make_float4(a0, a1, a2, a3);
    *(float4*)(op + (size_t)(row0 + orow) * WW + tc0) = o;
  }
}

extern "C" void kernel_launch(void* const* d_in, const int* in_sizes, int n_in,
                              void* d_out, int out_size, void* d_ws, size_t ws_size,
                              hipStream_t stream) {
  const float* x = (const float*)d_in[0];
  const float* w = (const float*)d_in[1];
  float* out = (float*)d_out;
  // 16 batches * 96 channels * 2 half-planes
  const int nblocks = 16 * CC * 2;
  morph_kernel<<<nblocks, 256, 0, stream>>>(x, w, out);
}